// Round 1
// baseline (8770.105 us; speedup 1.0000x reference)
//
#include <hip/hip_runtime.h>
#include <math.h>

constexpr int kB = 256;
constexpr int kT = 200;
constexpr int kD = 512;
constexpr int kU = 1024;
constexpr int kG = 4096;   // 4*U

typedef short frag8 __attribute__((ext_vector_type(8)));     // 8 bf16 (4 VGPRs)
typedef float floatx4 __attribute__((ext_vector_type(4)));   // MFMA C/D frag
typedef unsigned short ushort_t;

__device__ __forceinline__ ushort_t f2bf(float f) {
    union { float f; unsigned int u; } v; v.f = f;
    unsigned int r = v.u + 0x7fffu + ((v.u >> 16) & 1u);   // RNE
    return (ushort_t)(r >> 16);
}
__device__ __forceinline__ float bf2f(ushort_t h) {
    union { unsigned int u; float f; } v; v.u = ((unsigned int)h) << 16;
    return v.f;
}

// ---------------------------------------------------------------------------
// Repack [W (K1 rows); Uw (K-K1 rows)] fp32 [*,4096] -> bf16 fragment order.
// Gate-interleaved columns: n_new = 4*j + g  <->  n_old = g*1024 + j.
// frag8 addr (units): ((nb*nkb + kb)*4 + ct)*64 + lane  (verified, absmax 0.0)
// ---------------------------------------------------------------------------
__global__ __launch_bounds__(256)
void repack_weights(const float* __restrict__ W, const float* __restrict__ Uw,
                    int K1, int K, ushort_t* __restrict__ out)
{
    const int nkb = K >> 5;
    const int kb = blockIdx.x % nkb;
    const int nb = blockIdx.x / nkb;
    __shared__ ushort_t tile[2048];
    const int tid = threadIdx.x;
#pragma unroll
    for (int i = 0; i < 8; i++) {
        int idx  = tid + (i << 8);         // 0..2047
        int kl   = idx >> 6;               // 0..31
        int lcol = idx & 63;               // 0..63
        int g  = lcol >> 4;
        int jl = lcol & 15;
        int k  = (kb << 5) + kl;
        int n_old = (g << 10) + (nb << 4) + jl;
        float v = (k < K1) ? W[(long)k * kG + n_old]
                           : Uw[(long)(k - K1) * kG + n_old];
        int n_new_l = (jl << 2) + g;       // local packed column
        int ng = n_new_l >> 4, nl = n_new_l & 15;
        int quad = kl >> 3, e = kl & 7;
        tile[ng * 512 + (quad * 16 + nl) * 8 + e] = f2bf(v);
    }
    __syncthreads();
    long base = ((long)(nb * nkb + kb)) * 2048;
    *(frag8*)&out[base + tid * 8] = *(frag8*)&tile[tid * 8];
}

__global__ __launch_bounds__(256)
void repack_bias(const float* __restrict__ b1, const float* __restrict__ b2,
                 float* __restrict__ o1, float* __restrict__ o2)
{
    int n = blockIdx.x * blockDim.x + threadIdx.x;   // 0..4095
    int n_old = ((n & 3) << 10) + (n >> 2);
    o1[n] = b1[n_old];
    o2[n] = b2[n_old];
}

// One-time embedding gather + fp32->bf16: xbf[b*T+t][d].
__global__ __launch_bounds__(128)
void xgather(const int* __restrict__ tokens, const float* __restrict__ emb,
             ushort_t* __restrict__ xbf)
{
    int bt = blockIdx.x;
    int tok = tokens[bt];
    float4 v = *(const float4*)(emb + (long)tok * kD + threadIdx.x * 4);
    unsigned int lo = ((unsigned int)f2bf(v.y) << 16) | f2bf(v.x);
    unsigned int hi = ((unsigned int)f2bf(v.w) << 16) | f2bf(v.z);
    uint2 p; p.x = lo; p.y = hi;
    *(uint2*)(xbf + (long)bt * kD + threadIdx.x * 4) = p;
}

// ---------------------------------------------------------------------------
// Persistent weight-resident LSTM.
// 256 blocks x 256 thr (1 block/CU, pinned by 140KB LDS). Blocks 0..127 =
// layer2 (K=2048), 128..255 = layer1 (K=1536). Each block owns 32 packed
// gate-cols (= 8 h units), stages its weight slice to LDS ONCE, then loops
// over 201 merged time steps with a device-scope grid barrier per step.
// Wave tile: 64 rows x 32 cols -> acc[4][2]; c-state lives in registers.
// Same kb accumulation order as the previous kernel -> bitwise-identical z.
// ---------------------------------------------------------------------------
struct Batch { frag8 A[16]; frag8 B[8]; };

template<int K1KB>
__device__ __forceinline__ void load_batch(int bi, Batch& bb,
    const ushort_t* const (&a1p)[4], const ushort_t* const (&a2p)[4],
    const frag8* __restrict__ wl)
{
    const int kb0 = bi * 4;
#pragma unroll
    for (int u = 0; u < 4; u++) {
        const int kb = kb0 + u;
        bb.B[u*2+0] = wl[(kb*2+0) * 64];
        bb.B[u*2+1] = wl[(kb*2+1) * 64];
    }
    if (kb0 < K1KB) {      // batches are 4-kb aligned; K1KB % 4 == 0
#pragma unroll
        for (int u = 0; u < 4; u++)
#pragma unroll
            for (int i = 0; i < 4; i++)
                bb.A[u*4+i] = *(const frag8*)(a1p[i] + (kb0+u) * 32);
    } else {
#pragma unroll
        for (int u = 0; u < 4; u++)
#pragma unroll
            for (int i = 0; i < 4; i++)
                bb.A[u*4+i] = *(const frag8*)(a2p[i] + (kb0+u-K1KB) * 32);
    }
}

__device__ __forceinline__ void mfma_batch(const Batch& bb, floatx4 (&acc)[4][2])
{
#pragma unroll
    for (int u = 0; u < 4; u++)
#pragma unroll
        for (int mi = 0; mi < 4; mi++)
#pragma unroll
            for (int ct = 0; ct < 2; ct++)
                acc[mi][ct] = __builtin_amdgcn_mfma_f32_16x16x32_bf16(
                    bb.A[u*4+mi], bb.B[u*2+ct], acc[mi][ct], 0, 0, 0);
}

// Device-scope grid barrier. Release (wbl2) makes our h-stores visible at the
// coherence point; relaxed spin (no per-poll buffer_inv, which would trash
// neighbours' L2 hits); one acquire fence (buffer_inv) after the count trips.
__device__ __forceinline__ void grid_sync(unsigned* __restrict__ bar, unsigned target)
{
    __syncthreads();                 // drains vmcnt(0): all waves' stores in L2
    if (threadIdx.x == 0) {
        __hip_atomic_fetch_add(bar, 1u, __ATOMIC_RELEASE, __HIP_MEMORY_SCOPE_AGENT);
        while (__hip_atomic_load(bar, __ATOMIC_RELAXED, __HIP_MEMORY_SCOPE_AGENT) < target)
            __builtin_amdgcn_s_sleep(2);
        __builtin_amdgcn_fence(__ATOMIC_ACQUIRE, "agent");
    }
    __syncthreads();
}

template<int NKB, int K1KB>
__device__ __forceinline__ void step_block(
    const ushort_t* __restrict__ A1, long a1_rs, long a1_off,
    const ushort_t* __restrict__ A2,              // row stride kU
    const ushort_t* __restrict__ wlds_,
    float4 bias4, float (&creg)[4][2],
    ushort_t* __restrict__ hOut, int ub, float* __restrict__ zsw)
{
    const int tid = threadIdx.x, lane = tid & 63, wave = tid >> 6;
    const int wrow = wave << 6;                    // wave owns 64 rows
    const int r0 = wrow + (lane & 15);
    const int kq = (lane >> 4) << 3;

    const ushort_t* a1p[4]; const ushort_t* a2p[4];
#pragma unroll
    for (int i = 0; i < 4; i++) {
        a1p[i] = A1 + (long)(r0 + 16*i) * a1_rs + a1_off + kq;
        a2p[i] = A2 + (long)(r0 + 16*i) * kU + kq;
    }
    const frag8* wl = (const frag8*)wlds_ + lane;

    floatx4 acc[4][2];
#pragma unroll
    for (int i = 0; i < 4; i++) {
        acc[i][0] = (floatx4){0.f,0.f,0.f,0.f};
        acc[i][1] = (floatx4){0.f,0.f,0.f,0.f};
    }

    constexpr int NBATCH = NKB / 4;                // 16 (L2) or 12 (L1) — even
    Batch X, Y;
    load_batch<K1KB>(0, X, a1p, a2p, wl);
#pragma unroll 1
    for (int bi = 0; bi < NBATCH; bi += 2) {
        load_batch<K1KB>(bi + 1, Y, a1p, a2p, wl);
        mfma_batch(X, acc);
        if (bi + 2 < NBATCH) load_batch<K1KB>(bi + 2, X, a1p, a2p, wl);
        mfma_batch(Y, acc);
    }

    // Epilogue: per-wave LDS transpose (intra-wave DS FIFO ordering), fp32 gates.
    const int q = lane >> 4, c16 = lane & 15;
    const int rl0 = lane >> 3, jl = lane & 7;      // jl constant per lane
#pragma unroll
    for (int mi = 0; mi < 4; mi++) {
#pragma unroll
        for (int ct = 0; ct < 2; ct++)
#pragma unroll
            for (int r = 0; r < 4; r++)
                zsw[((q << 2) + r) * 36 + (ct << 4) + c16] = acc[mi][ct][r];
#pragma unroll
        for (int ii = 0; ii < 2; ii++) {
            int rowl = rl0 + (ii << 3);
            float4 z4 = *(float4*)&zsw[rowl * 36 + (jl << 2)];
            float zi = z4.x + bias4.x, zf = z4.y + bias4.y;
            float zg = z4.z + bias4.z, zo = z4.w + bias4.w;
            float ig = 1.f / (1.f + __expf(-zi));
            float fg = 1.f / (1.f + __expf(-zf));
            float og = 1.f / (1.f + __expf(-zo));
            float gg = 1.f - 2.f / (__expf(2.f * zg) + 1.f);   // tanh
            float cn = fg * creg[mi][ii] + ig * gg;
            creg[mi][ii] = cn;
            float tc = 1.f - 2.f / (__expf(2.f * cn) + 1.f);   // tanh
            int m = wrow + (mi << 4) + rowl;
            hOut[(long)m * kU + ub + jl] = f2bf(og * tc);
        }
    }
}

__global__ __launch_bounds__(256, 1)
void lstm_persist(const ushort_t* __restrict__ W1p, const ushort_t* __restrict__ W2p,
                  const float* __restrict__ b1p, const float* __restrict__ b2p,
                  const ushort_t* __restrict__ xbf,
                  ushort_t* __restrict__ h1a, ushort_t* __restrict__ h1b,
                  ushort_t* __restrict__ h2a, ushort_t* __restrict__ h2b,
                  unsigned* __restrict__ bar)
{
    __shared__ __align__(16) ushort_t wlds[65536];   // 128 KB weight slice
    __shared__ __align__(16) float zs[4][576];       // 9 KB epilogue transpose

    const int bid = blockIdx.x;
    const bool isL2 = bid < 128;
    const int b = isL2 ? bid : bid - 128;            // 0..127: owns cols 32b..32b+31
    const int tid = threadIdx.x, lane = tid & 63, wave = tid >> 6;

    // ---- one-time: stage weight slice into LDS ----
    {
        const frag8* wg = (const frag8*)(isL2 ? W2p : W1p);
        const int NKB = isL2 ? 64 : 48;
        const int nb2 = b >> 1, cbase = (b & 1) * 2;
        const long gb = (long)nb2 * NKB * 256;       // frag8 units
        frag8* wl = (frag8*)wlds;
        for (int i = tid; i < NKB * 128; i += 256) {
            int kb = i >> 7, r = i & 127;
            wl[i] = wg[gb + ((long)kb * 4 + cbase + (r >> 6)) * 64 + (r & 63)];
        }
    }

    const float4* biasP4 = (const float4*)(isL2 ? b2p : b1p);
    const float4 bias4 = biasP4[b * 8 + (lane & 7)]; // this lane's 4 gate biases

    float creg[4][2];                                // c-state: 8 fp32/lane, whole seq
#pragma unroll
    for (int i = 0; i < 4; i++) { creg[i][0] = 0.f; creg[i][1] = 0.f; }

    float* zsw = zs[wave];
    const int ub = b << 3;                           // h-unit column base

    __syncthreads();                                 // weights staged

#pragma unroll 1
    for (int l = 0; l <= kT; l++) {
        ushort_t* h1cur = (l & 1) ? h1b : h1a;       // h1[l&1]
        ushort_t* h1nxt = (l & 1) ? h1a : h1b;       // h1[(l+1)&1]
        ushort_t* h2prv = (l & 1) ? h2a : h2b;       // h2[(l-1)&1]
        ushort_t* h2cur = (l & 1) ? h2b : h2a;       // h2[l&1]
        if (isL2) {
            if (l >= 1)                              // t2 = l-1
                step_block<64, 32>(h1cur, kU, 0, h2prv, wlds,
                                   bias4, creg, h2cur, ub, zsw);
        } else {
            if (l < kT)                              // t1 = l
                step_block<48, 16>(xbf, (long)kT * kD, (long)l * kD, h1cur, wlds,
                                   bias4, creg, h1nxt, ub, zsw);
        }
        grid_sync(bar, 256u * (unsigned)(l + 1));
    }
}

// out[b] = sigmoid(h[b,:] . Wfc + bfc), h in bf16
__global__ __launch_bounds__(256)
void fc_sigmoid(const ushort_t* __restrict__ h, const float* __restrict__ Wfc,
                const float* __restrict__ bfc, float* __restrict__ out)
{
    int b = blockIdx.x, tid = threadIdx.x;
    float s = 0.f;
    for (int j = tid; j < kU; j += 256) s += bf2f(h[(long)b * kU + j]) * Wfc[j];
    __shared__ float red[4];
    for (int off = 32; off > 0; off >>= 1) s += __shfl_down(s, off, 64);
    if ((tid & 63) == 0) red[tid >> 6] = s;
    __syncthreads();
    if (tid == 0) {
        float t = red[0] + red[1] + red[2] + red[3] + bfc[0];
        out[b] = 1.f / (1.f + expf(-t));
    }
}

extern "C" void kernel_launch(void* const* d_in, const int* in_sizes, int n_in,
                              void* d_out, int out_size, void* d_ws, size_t ws_size,
                              hipStream_t stream)
{
    (void)in_sizes; (void)n_in; (void)out_size; (void)ws_size;

    const int*   tokens = (const int*)d_in[0];
    const float* emb    = (const float*)d_in[1];
    const float* W1     = (const float*)d_in[2];
    const float* U1     = (const float*)d_in[3];
    const float* b1     = (const float*)d_in[4];
    const float* W2     = (const float*)d_in[5];
    const float* U2     = (const float*)d_in[6];
    const float* b2     = (const float*)d_in[7];
    const float* Wfc    = (const float*)d_in[8];
    const float* bfc    = (const float*)d_in[9];
    float* out = (float*)d_out;

    // Workspace: ~84 MB
    ushort_t* W1p = (ushort_t*)d_ws;                       // [1536*4096] bf16
    ushort_t* W2p = W1p + (size_t)1536 * kG;               // [2048*4096] bf16
    float* b1p = (float*)(W2p + (size_t)2048 * kG);        // [4096] f32
    float* b2p = b1p + kG;                                 // [4096] f32
    ushort_t* hbuf = (ushort_t*)(b2p + kG);                // 4 x [256*1024] bf16
    ushort_t* h1a = hbuf;
    ushort_t* h1b = hbuf + (size_t)kB * kU;
    ushort_t* h2a = hbuf + 2 * (size_t)kB * kU;
    ushort_t* h2b = hbuf + 3 * (size_t)kB * kU;
    unsigned* bar = (unsigned*)(hbuf + 4 * (size_t)kB * kU);
    ushort_t* xbf = (ushort_t*)(bar + 16);                 // [B*T*512] bf16 (16B aligned)

    repack_weights<<<48 * 64, 256, 0, stream>>>(W1, U1, 512, 1536, W1p);
    repack_weights<<<64 * 64, 256, 0, stream>>>(W2, U2, 1024, 2048, W2p);
    repack_bias<<<16, 256, 0, stream>>>(b1, b2, b1p, b2p);
    xgather<<<kB * kT, 128, 0, stream>>>(tokens, emb, xbf);
    // zero h buffers (bf16) + barrier counter: contiguous 2 MB + 64 B
    hipMemsetAsync(hbuf, 0, 4 * (size_t)kB * kU * sizeof(ushort_t) + 64, stream);

    void* args[] = { &W1p, &W2p, &b1p, &b2p, &xbf,
                     &h1a, &h1b, &h2a, &h2b, &bar };
    hipLaunchCooperativeKernel((void*)lstm_persist, dim3(256), dim3(256),
                               args, 0, stream);

    // final h2 written at l=200 (even) -> h2a
    fc_sigmoid<<<kB, 256, 0, stream>>>(h2a, Wfc, bfc, out);
}